// Round 12
// baseline (225.090 us; speedup 1.0000x reference)
//
#include <hip/hip_runtime.h>
#include <math.h>

#define HID 2048
#define TOKENS 4096   // B*T
#define TT 2048       // T
#define NCH 4096      // B*HID independent scan channels
#define NC 32         // scan chunks along T
#define CL 64         // chunk length = TT/NC
#define WELEM 4194304 // 2048*2048

typedef unsigned short u16;
typedef signed char i8;
typedef int i32x4 __attribute__((ext_vector_type(4)));

__device__ inline float sigm(float x) { return 1.0f / (1.0f + expf(-x)); }
// bf16 round-to-nearest-even and back
__device__ inline u16 f2bf_rn(float v) {
  unsigned b = __float_as_uint(v);
  unsigned r = b + 0x7FFFu + ((b >> 16) & 1u);
  return (u16)(r >> 16);
}
__device__ inline float bf2f(u16 h) {
  return __uint_as_float((unsigned)h << 16);
}

__device__ inline float wred_sum(float v) {
#pragma unroll
  for (int o = 32; o > 0; o >>= 1) v += __shfl_down(v, o);
  return v;
}
__device__ inline float wred_max(float v) {
#pragma unroll
  for (int o = 32; o > 0; o >>= 1) v = fmaxf(v, __shfl_down(v, o));
  return v;
}
__device__ inline double wred_sumd(double v) {
#pragma unroll
  for (int o = 32; o > 0; o >>= 1) v += __shfl_down(v, o);
  return v;
}

// async global->LDS, 16B per lane; LDS dest = wave-uniform base + lane*16
__device__ __forceinline__ void gl_lds16(const void* g, void* l) {
  __builtin_amdgcn_global_load_lds(
      (__attribute__((address_space(1))) void*)(void*)g,
      (__attribute__((address_space(3))) void*)l, 16, 0, 0);
}

__device__ __forceinline__ int pack8(const int* qi) {
  return (qi[0] & 255) | ((qi[1] & 255) << 8) | ((qi[2] & 255) << 16)
       | ((qi[3] & 255) << 24);
}

// ---------------- K1: mean(|w|) for the 4 weights, f64 accumulation -------
__global__ __launch_bounds__(256) void absmean_kernel(
    const float* __restrict__ w0, const float* __restrict__ w1,
    const float* __restrict__ w2, const float* __restrict__ w3,
    double* __restrict__ wsum) {
  int widx = blockIdx.x >> 9;
  int blk = blockIdx.x & 511;
  const float* w = widx == 0 ? w0 : widx == 1 ? w1 : widx == 2 ? w2 : w3;
  size_t base = (size_t)blk * 8192;
  double acc = 0.0;
#pragma unroll
  for (int r = 0; r < 8; ++r) {
    float4 v = *(const float4*)&w[base + (size_t)(r * 256 + threadIdx.x) * 4];
    acc += (double)fabsf(v.x) + (double)fabsf(v.y) + (double)fabsf(v.z) +
           (double)fabsf(v.w);
  }
  acc = wred_sumd(acc);
  __shared__ double sh[4];
  int tid = threadIdx.x;
  if ((tid & 63) == 0) sh[tid >> 6] = acc;
  __syncthreads();
  if (tid == 0) atomicAdd(&wsum[widx], (sh[0] + sh[1]) + (sh[2] + sh[3]));
}

// ---------------- K2: fused weight-quant (x4) + act RMSNorm-quant (x3) ----
__global__ __launch_bounds__(256) void prep_kernel(
    const float* __restrict__ w0, const float* __restrict__ w1,
    const float* __restrict__ w2, const float* __restrict__ w3,
    const double* __restrict__ wsum, i8* __restrict__ q0, i8* __restrict__ q1,
    i8* __restrict__ q2, i8* __restrict__ q3, const float* __restrict__ X,
    const float* __restrict__ nw0, const float* __restrict__ nw1,
    const float* __restrict__ nw2, i8* __restrict__ Xq0, i8* __restrict__ Xq1,
    i8* __restrict__ Xq2, float* __restrict__ inv0, float* __restrict__ inv1,
    float* __restrict__ inv2) {
  if (blockIdx.x < 8192) {
    int sel = blockIdx.x >> 11;  // 0..3
    int blk = blockIdx.x & 2047;
    const float* w = sel == 0 ? w0 : sel == 1 ? w1 : sel == 2 ? w2 : w3;
    i8* wq = sel == 0 ? q0 : sel == 1 ? q1 : sel == 2 ? q2 : q3;
    int widx = sel == 0 ? 1 : sel == 1 ? 0 : sel;
    double mean = wsum[widx] * (1.0 / (double)WELEM);
    float s = (float)(1.0 / fmax(mean, 1e-5));
    size_t base = (size_t)blk * 2048 + (size_t)threadIdx.x * 8;
    float4 va = *(const float4*)&w[base];
    float4 vb = *(const float4*)&w[base + 4];
    float vv[8] = {va.x, va.y, va.z, va.w, vb.x, vb.y, vb.z, vb.w};
    int qi[8];
#pragma unroll
    for (int j = 0; j < 8; ++j) {
      float q1v = rintf(vv[j] * s);
      q1v = fminf(fmaxf(q1v, -1.0f), 1.0f);
      qi[j] = (int)q1v;
    }
    *(int2*)&wq[base] = make_int2(pack8(qi), pack8(qi + 4));
    return;
  }
  int tok = blockIdx.x - 8192;
  int tid = threadIdx.x;
  const float* xrow = X + (size_t)tok * HID;
  int c0 = tid * 8;
  float x[8];
  *(float4*)&x[0] = *(const float4*)&xrow[c0];
  *(float4*)&x[4] = *(const float4*)&xrow[c0 + 4];
  float ss = 0.0f;
#pragma unroll
  for (int j = 0; j < 8; ++j) ss += x[j] * x[j];
  __shared__ float sh[4];
  float v = wred_sum(ss);
  if ((tid & 63) == 0) sh[tid >> 6] = v;
  __syncthreads();
  float tot = (sh[0] + sh[1]) + (sh[2] + sh[3]);
  float rstd = (float)(1.0 / sqrt((double)(tot * (1.0f / HID)) + 1e-8));
#pragma unroll
  for (int pass = 0; pass < 3; ++pass) {
    const float* nw = pass == 0 ? nw0 : pass == 1 ? nw1 : nw2;
    i8* Xq = pass == 0 ? Xq0 : pass == 1 ? Xq1 : Xq2;
    float* inv_s = pass == 0 ? inv0 : pass == 1 ? inv1 : inv2;
    float y[8];
    float amax = 0.0f;
#pragma unroll
    for (int j = 0; j < 8; ++j) {
      y[j] = x[j] * rstd * nw[c0 + j];
      amax = fmaxf(amax, fabsf(y[j]));
    }
    __syncthreads();
    float vv = wred_max(amax);
    if ((tid & 63) == 0) sh[tid >> 6] = vv;
    __syncthreads();
    float am = fmaxf(fmaxf(fmaxf(sh[0], sh[1]), fmaxf(sh[2], sh[3])), 1e-5f);
    float s = 127.0f / am;
    int qi[8];
#pragma unroll
    for (int j = 0; j < 8; ++j) {
      float qq = rintf(y[j] * s);
      qq = fminf(fmaxf(qq, -128.0f), 127.0f);
      qi[j] = (int)qq;
    }
    *(int2*)&Xq[(size_t)tok * HID + c0] = make_int2(pack8(qi), pack8(qi + 4));
    if (tid == 0) inv_s[tok] = am * (1.0f / 127.0f);
  }
}

// ---------------- K4: i8 MFMA GEMM, counted-vmcnt ring pipeline -----------
// out[m,n] = sum_k A[m,k]*W[n,k]; i32 accumulate (exact).
// Block 128(M) x 256(N), 8 waves (wm=wave>>2 in{0,1}, wn=wave&3): wave owns
// 64x64 (acc 4x4). K = 32 "units" of 64B (half of a 128B K-tile). LDS is a
// ring of 4 units per matrix: A-plane 128x64B (8KB), B-plane 256x64B (16KB)
// -> 96KB, 1 block/CU. Steady state per unit:
//   vmcnt(6)          // retire unit u's 3 loads; u+1,u+2's 6 stay in flight
//   s_barrier         // everyone's unit-u loads landed; unit u-1 reads done
//   {8 ds_read, stage unit u+3 -> slot (u-1)&3 (3 gl_lds), 16 MFMA+setprio}
// No vmcnt(0)/lgkmcnt(0) drain in the steady loop; loads get ~3 units of
// cover. Race-safety: a wave can only stage into slot s after the barrier
// that proves all waves' reads of s's previous occupant completed (reads
// complete before each wave's MFMAs, which precede its barrier arrival).
// Swizzle (64B plane rows, 4 16B slots): phys = logical ^ ((row>>1)&3);
// inverse applied on the gl_lds global source, forward on ds_read ->
// 2 lanes/bank max (free).
template <int NSEG, bool F32OUT>
__global__ __launch_bounds__(512, 2) void gemm256_kernel(
    const i8* __restrict__ A0, const i8* __restrict__ A1,
    const i8* __restrict__ A2, const i8* __restrict__ W0,
    const i8* __restrict__ W1, const i8* __restrict__ W2,
    const float* __restrict__ inv0, const float* __restrict__ inv1,
    const float* __restrict__ inv2, const double* __restrict__ wsum,
    int widx0, int widx1, int widx2, void* __restrict__ O0,
    void* __restrict__ O1, void* __restrict__ O2) {
  const int tid = threadIdx.x;
  // XCD-aware bijective swizzle (gridDim.x % 8 == 0)
  const int cpx = gridDim.x >> 3;
  const int lid = blockIdx.x;
  const int swz = (lid & 7) * cpx + (lid >> 3);
  const int seg = NSEG == 1 ? 0 : (swz >> 8);  // 256 blocks per segment
  const int idx = swz & 255;
  const int n0 = (idx & 7) * 256;   // 8 n-tiles (HID/256)
  const int m0 = (idx >> 3) * 128;  // 32 m-tiles (TOKENS/128)

  const i8* Aq = seg == 0 ? A0 : seg == 1 ? A1 : A2;
  const i8* Wq = seg == 0 ? W0 : seg == 1 ? W1 : W2;
  const float* inv_s = seg == 0 ? inv0 : seg == 1 ? inv1 : inv2;
  void* Out = seg == 0 ? O0 : seg == 1 ? O1 : O2;
  const int widx = seg == 0 ? widx0 : seg == 1 ? widx1 : widx2;

  __shared__ __align__(16) i8 Apl[4][8192];   // 4 units x 128 rows x 64B
  __shared__ __align__(16) i8 Bpl[4][16384];  // 4 units x 256 rows x 64B
  float wscale = (float)fmax(wsum[widx] * (1.0 / (double)WELEM), 1e-5);

  const int wave = tid >> 6, lane = tid & 63;
  const int wm = wave >> 2;  // M half (64 rows of 128)
  const int wn = wave & 3;   // N quarter (64 cols of 256)
  const int lrow = lane & 15;
  const int ksel = lane >> 4;  // 16B quarter within 64B plane row
  const int rdcol = ((ksel ^ ((lrow >> 1) & 3)) << 4);  // swizzled read col
  const int srow = lane >> 2;  // row within a 16-row staging chunk
  const int scol = (((lane & 3) ^ ((lane >> 3) & 3)) << 4);  // inv-swz src

  const i8* Ab = Aq + (size_t)m0 * HID;
  const i8* Wb = Wq + (size_t)n0 * HID;

  i32x4 acc[4][4];
#pragma unroll
  for (int i = 0; i < 4; ++i)
#pragma unroll
    for (int j = 0; j < 4; ++j)
#pragma unroll
      for (int r = 0; r < 4; ++r) acc[i][j][r] = 0;

  // unit u: k-bytes [ (u>>1)*128 + (u&1)*64 .. +64 ), ring slot u&3.
  // per wave per unit: A chunk 'wave' (16 rows), B chunks 2w, 2w+1.
#define STAGEU0(u_)                                                         \
  {                                                                         \
    int kb = ((u_) >> 1) * 128 + ((u_)&1) * 64;                             \
    int sl = (u_)&3;                                                        \
    gl_lds16(&Ab[(size_t)(wave * 16 + srow) * HID + kb + scol],             \
             &Apl[sl][wave * 1024]);                                        \
    gl_lds16(&Wb[(size_t)(wave * 32 + srow) * HID + kb + scol],             \
             &Bpl[sl][wave * 2048]);                                        \
  }
#define STAGEU1(u_)                                                         \
  {                                                                         \
    int kb = ((u_) >> 1) * 128 + ((u_)&1) * 64;                             \
    int sl = (u_)&3;                                                        \
    gl_lds16(&Wb[(size_t)(wave * 32 + 16 + srow) * HID + kb + scol],        \
             &Bpl[sl][wave * 2048 + 1024]);                                 \
  }

  // prologue: units 0,1,2 in flight (9 loads, FIFO by unit)
  STAGEU0(0) STAGEU1(0) STAGEU0(1) STAGEU1(1) STAGEU0(2) STAGEU1(2)

  for (int u = 0; u < 32; ++u) {
    if (u < 30)
      asm volatile("s_waitcnt vmcnt(6)" ::: "memory");
    else if (u == 30)
      asm volatile("s_waitcnt vmcnt(3)" ::: "memory");
    else
      asm volatile("s_waitcnt vmcnt(0)" ::: "memory");
    __builtin_amdgcn_s_barrier();
    const int sl = u & 3;
    i32x4 af0, af1, bf[4];
    // ---- sub 0: M-frags 0,1 ----
    af0 = *(const i32x4*)&Apl[sl][(wm * 64 + 0 * 16 + lrow) * 64 + rdcol];
    af1 = *(const i32x4*)&Apl[sl][(wm * 64 + 1 * 16 + lrow) * 64 + rdcol];
#pragma unroll
    for (int j = 0; j < 4; ++j)
      bf[j] = *(const i32x4*)&Bpl[sl][(wn * 64 + j * 16 + lrow) * 64 + rdcol];
    if (u < 29) STAGEU0(u + 3)
    __builtin_amdgcn_s_setprio(1);
#pragma unroll
    for (int j = 0; j < 4; ++j) {
      acc[0][j] = __builtin_amdgcn_mfma_i32_16x16x64_i8(af0, bf[j], acc[0][j],
                                                        0, 0, 0);
      acc[1][j] = __builtin_amdgcn_mfma_i32_16x16x64_i8(af1, bf[j], acc[1][j],
                                                        0, 0, 0);
    }
    __builtin_amdgcn_s_setprio(0);
    // ---- sub 1: M-frags 2,3 (bf reused) ----
    af0 = *(const i32x4*)&Apl[sl][(wm * 64 + 2 * 16 + lrow) * 64 + rdcol];
    af1 = *(const i32x4*)&Apl[sl][(wm * 64 + 3 * 16 + lrow) * 64 + rdcol];
    if (u < 29) STAGEU1(u + 3)
    __builtin_amdgcn_s_setprio(1);
#pragma unroll
    for (int j = 0; j < 4; ++j) {
      acc[2][j] = __builtin_amdgcn_mfma_i32_16x16x64_i8(af0, bf[j], acc[2][j],
                                                        0, 0, 0);
      acc[3][j] = __builtin_amdgcn_mfma_i32_16x16x64_i8(af1, bf[j], acc[3][j],
                                                        0, 0, 0);
    }
    __builtin_amdgcn_s_setprio(0);
  }
#undef STAGEU0
#undef STAGEU1

#pragma unroll
  for (int mi = 0; mi < 4; ++mi) {
    int rbase = m0 + wm * 64 + mi * 16 + (lane >> 4) * 4;
#pragma unroll
    for (int j = 0; j < 4; ++j) {
      int col = n0 + wn * 64 + j * 16 + lrow;
#pragma unroll
      for (int r = 0; r < 4; ++r) {
        int row = rbase + r;
        float v = (float)acc[mi][j][r] * inv_s[row] * wscale;
        float rr;
        if (NSEG == 3)
          rr = seg == 0 ? sigm(v) : seg == 1 ? v * sigm(v) : v;
        else
          rr = v;
        size_t oidx = (size_t)row * HID + col;
        if (F32OUT)
          ((float*)Out)[oidx] = rr;
        else
          ((u16*)Out)[oidx] = f2bf_rn(rr);
      }
    }
  }
}

// ---------------- K5: chunked parallel scan h = f*h + silu_i*(1-f) --------
__global__ __launch_bounds__(256) void scan1_kernel(
    const u16* __restrict__ F, u16* __restrict__ IO, float* __restrict__ P,
    float* __restrict__ H) {
  int c = blockIdx.x * 256 + threadIdx.x;
  int q = blockIdx.y;
  size_t base =
      (size_t)(c >> 11) * TT * HID + (c & 2047) + (size_t)q * CL * HID;
  float h = 0.0f, p = 1.0f;
#pragma unroll 4
  for (int t = 0; t < CL; ++t) {
    size_t idx = base + (size_t)t * HID;
    float f = bf2f(F[idx]);
    float iv = bf2f(IO[idx]);
    h = fmaf(f, h, iv - iv * f);  // f*h + silu_i*(1-f)
    p *= f;
    IO[idx] = f2bf_rn(h);
  }
  P[q * NCH + c] = p;
  H[q * NCH + c] = h;
}

__global__ __launch_bounds__(256) void scan23_kernel(
    const u16* __restrict__ F, const float* __restrict__ P,
    const float* __restrict__ H, u16* __restrict__ IO) {
  int c = blockIdx.x * 256 + threadIdx.x;
  int q = blockIdx.y + 1;  // chunk 0 needs no fixup
  float carry = 0.0f;
  for (int qq = 0; qq < q; ++qq)
    carry = fmaf(P[qq * NCH + c], carry, H[qq * NCH + c]);
  if (carry == 0.0f) return;
  size_t base =
      (size_t)(c >> 11) * TT * HID + (c & 2047) + (size_t)q * CL * HID;
  float p = 1.0f;
#pragma unroll 4
  for (int t = 0; t < CL; ++t) {
    size_t idx = base + (size_t)t * HID;
    p *= bf2f(F[idx]);
    IO[idx] = f2bf_rn(fmaf(p, carry, bf2f(IO[idx])));
  }
}

// ---------------- K6: fused  o=rms(g)*o*sigm(o)  ->  rms(o,n_o)+quant -----
__global__ __launch_bounds__(256) void combine_quant_kernel(
    const u16* __restrict__ G, const float* __restrict__ gnw,
    const u16* __restrict__ O, const float* __restrict__ nw,
    i8* __restrict__ Xq, float* __restrict__ inv_s) {
  int tok = blockIdx.x;
  int tid = threadIdx.x;
  int c0 = tid * 8;
  const u16* grow = G + (size_t)tok * HID;
  const u16* orow = O + (size_t)tok * HID;
  ushort4 ga = *(const ushort4*)&grow[c0];
  ushort4 gb = *(const ushort4*)&grow[c0 + 4];
  ushort4 oa = *(const ushort4*)&orow[c0];
  ushort4 ob = *(const ushort4*)&orow[c0 + 4];
  float g[8] = {bf2f(ga.x), bf2f(ga.y), bf2f(ga.z), bf2f(ga.w),
                bf2f(gb.x), bf2f(gb.y), bf2f(gb.z), bf2f(gb.w)};
  float o[8] = {bf2f(oa.x), bf2f(oa.y), bf2f(oa.z), bf2f(oa.w),
                bf2f(ob.x), bf2f(ob.y), bf2f(ob.z), bf2f(ob.w)};
  __shared__ float sh[4];
  float ss = 0.0f;
#pragma unroll
  for (int j = 0; j < 8; ++j) ss += g[j] * g[j];
  float v = wred_sum(ss);
  if ((tid & 63) == 0) sh[tid >> 6] = v;
  __syncthreads();
  float tot = (sh[0] + sh[1]) + (sh[2] + sh[3]);
  float rstd_g = (float)(1.0 / sqrt((double)(tot * (1.0f / HID)) + 1e-5));
  float on[8];
  float ss2 = 0.0f;
#pragma unroll
  for (int j = 0; j < 8; ++j) {
    on[j] = g[j] * rstd_g * gnw[c0 + j] * o[j] * sigm(o[j]);
    ss2 += on[j] * on[j];
  }
  __syncthreads();
  v = wred_sum(ss2);
  if ((tid & 63) == 0) sh[tid >> 6] = v;
  __syncthreads();
  float tot2 = (sh[0] + sh[1]) + (sh[2] + sh[3]);
  float rstd_o = (float)(1.0 / sqrt((double)(tot2 * (1.0f / HID)) + 1e-8));
  float y[8];
  float amax = 0.0f;
#pragma unroll
  for (int j = 0; j < 8; ++j) {
    y[j] = on[j] * rstd_o * nw[c0 + j];
    amax = fmaxf(amax, fabsf(y[j]));
  }
  __syncthreads();
  v = wred_max(amax);
  if ((tid & 63) == 0) sh[tid >> 6] = v;
  __syncthreads();
  float am = fmaxf(fmaxf(fmaxf(sh[0], sh[1]), fmaxf(sh[2], sh[3])), 1e-5f);
  float s = 127.0f / am;
  int qi[8];
#pragma unroll
  for (int j = 0; j < 8; ++j) {
    float qq = rintf(y[j] * s);
    qq = fminf(fmaxf(qq, -128.0f), 127.0f);
    qi[j] = (int)qq;
  }
  *(int2*)&Xq[(size_t)tok * HID + c0] = make_int2(pack8(qi), pack8(qi + 4));
  if (tid == 0) inv_s[tok] = am * (1.0f / 127.0f);
}

extern "C" void kernel_launch(void* const* d_in, const int* in_sizes, int n_in,
                              void* d_out, int out_size, void* d_ws,
                              size_t ws_size, hipStream_t stream) {
  const float* hs = (const float*)d_in[0];
  const float* w_i = (const float*)d_in[1];
  const float* w_f = (const float*)d_in[2];
  const float* w_g = (const float*)d_in[3];
  const float* w_o = (const float*)d_in[4];
  const float* n_i = (const float*)d_in[5];
  const float* n_f = (const float*)d_in[6];
  const float* n_g = (const float*)d_in[7];
  const float* n_o = (const float*)d_in[8];
  const float* gn_w = (const float*)d_in[9];
  float* Out = (float*)d_out;

  char* ws = (char*)d_ws;
  // Layout (~93.4MB of ~256MB ws)
  i8* WQ0 = (i8*)ws;                       // w_f ternary
  i8* WQ1 = (i8*)(ws + 4194304);           // w_i
  i8* WQ2 = (i8*)(ws + 8388608);           // w_g
  i8* WQ3 = (i8*)(ws + 12582912);          // w_o
  i8* XQ0 = (i8*)(ws + 16777216);          // f-quant, later o-quant
  i8* XQ1 = (i8*)(ws + 25165824);          // i-quant
  i8* XQ2 = (i8*)(ws + 33554432);          // g-quant
  u16* F = (u16*)(ws + 41943040);          // f gate (bf16)
  u16* OB = (u16*)(ws + 58720256);         // i -> scan h -> o (bf16)
  u16* G = (u16*)(ws + 75497472);          // g (bf16)
  float* invs0 = (float*)(ws + 92274688);
  float* invs1 = (float*)(ws + 92291072);
  float* invs2 = (float*)(ws + 92307456);
  double* wsum = (double*)(ws + 92323840);
  float* scanP = (float*)(ws + 92324864);
  float* scanH = (float*)(ws + 92849152);

  hipMemsetAsync(wsum, 0, 4 * sizeof(double), stream);
  // wsum order: 0=i, 1=f, 2=g, 3=o
  absmean_kernel<<<2048, 256, 0, stream>>>(w_i, w_f, w_g, w_o, wsum);

  // fused: quantize all 4 weights + 3 activation norms in one launch
  prep_kernel<<<12288, 256, 0, stream>>>(w_f, w_i, w_g, w_o, wsum, WQ0, WQ1,
                                         WQ2, WQ3, hs, n_f, n_i, n_g, XQ0,
                                         XQ1, XQ2, invs0, invs1, invs2);

  // merged: F = sigm(hs*Wf), OB = silu(hs*Wi), G = hs*Wg  (768 blocks)
  gemm256_kernel<3, false><<<768, 512, 0, stream>>>(
      XQ0, XQ1, XQ2, WQ0, WQ1, WQ2, invs0, invs1, invs2, wsum, 1, 0, 2, F, OB,
      G);

  // scan: h_t = f_t*h + silu_i_t*(1-f_t), in-place in OB (bf16)
  scan1_kernel<<<dim3(NCH / 256, NC), 256, 0, stream>>>(F, OB, scanP, scanH);
  scan23_kernel<<<dim3(NCH / 256, NC - 1), 256, 0, stream>>>(F, scanP, scanH,
                                                             OB);

  // fused: o = rms(g)*o*sigm(o); then rms(o, n_o) + act-quant -> XQ0
  combine_quant_kernel<<<TOKENS, 256, 0, stream>>>(G, gn_w, OB, n_o, XQ0,
                                                   invs0);

  // out = bitlinear(o, w_o, n_o)  (f32 output, 256 blocks = 1/CU)
  gemm256_kernel<1, true><<<256, 512, 0, stream>>>(
      XQ0, XQ0, XQ0, WQ3, WQ3, WQ3, invs0, invs0, invs0, wsum, 3, 3, 3, Out,
      Out, Out);
}

// Round 13
// 198.087 us; speedup vs baseline: 1.1363x; 1.1363x over previous
//
#include <hip/hip_runtime.h>
#include <math.h>

#define HID 2048
#define TOKENS 4096   // B*T
#define TT 2048       // T
#define NCH 4096      // B*HID independent scan channels
#define NC 32         // scan chunks along T
#define CL 64         // chunk length = TT/NC
#define WELEM 4194304 // 2048*2048

typedef unsigned short u16;
typedef signed char i8;
typedef int i32x4 __attribute__((ext_vector_type(4)));

__device__ inline float sigm(float x) { return 1.0f / (1.0f + expf(-x)); }
// bf16 round-to-nearest-even and back
__device__ inline u16 f2bf_rn(float v) {
  unsigned b = __float_as_uint(v);
  unsigned r = b + 0x7FFFu + ((b >> 16) & 1u);
  return (u16)(r >> 16);
}
__device__ inline float bf2f(u16 h) {
  return __uint_as_float((unsigned)h << 16);
}

__device__ inline float wred_sum(float v) {
#pragma unroll
  for (int o = 32; o > 0; o >>= 1) v += __shfl_down(v, o);
  return v;
}
__device__ inline float wred_max(float v) {
#pragma unroll
  for (int o = 32; o > 0; o >>= 1) v = fmaxf(v, __shfl_down(v, o));
  return v;
}
__device__ inline double wred_sumd(double v) {
#pragma unroll
  for (int o = 32; o > 0; o >>= 1) v += __shfl_down(v, o);
  return v;
}

// async global->LDS, 16B per lane; LDS dest = wave-uniform base + lane*16
__device__ __forceinline__ void gl_lds16(const void* g, void* l) {
  __builtin_amdgcn_global_load_lds(
      (__attribute__((address_space(1))) void*)(void*)g,
      (__attribute__((address_space(3))) void*)l, 16, 0, 0);
}

__device__ __forceinline__ int pack8(const int* qi) {
  return (qi[0] & 255) | ((qi[1] & 255) << 8) | ((qi[2] & 255) << 16)
       | ((qi[3] & 255) << 24);
}

// ---------------- K1: mean(|w|) for the 4 weights, f64 accumulation -------
__global__ __launch_bounds__(256) void absmean_kernel(
    const float* __restrict__ w0, const float* __restrict__ w1,
    const float* __restrict__ w2, const float* __restrict__ w3,
    double* __restrict__ wsum) {
  int widx = blockIdx.x >> 9;
  int blk = blockIdx.x & 511;
  const float* w = widx == 0 ? w0 : widx == 1 ? w1 : widx == 2 ? w2 : w3;
  size_t base = (size_t)blk * 8192;
  double acc = 0.0;
#pragma unroll
  for (int r = 0; r < 8; ++r) {
    float4 v = *(const float4*)&w[base + (size_t)(r * 256 + threadIdx.x) * 4];
    acc += (double)fabsf(v.x) + (double)fabsf(v.y) + (double)fabsf(v.z) +
           (double)fabsf(v.w);
  }
  acc = wred_sumd(acc);
  __shared__ double sh[4];
  int tid = threadIdx.x;
  if ((tid & 63) == 0) sh[tid >> 6] = acc;
  __syncthreads();
  if (tid == 0) atomicAdd(&wsum[widx], (sh[0] + sh[1]) + (sh[2] + sh[3]));
}

// ---------------- K2: fused weight-quant (x4) + act RMSNorm-quant (x3) ----
// blocks 0..8191: ternary-quantize the four weight matrices
// blocks 8192..12287: per-token RMSNorm + 8-bit fake quant, 3 norm weights
__global__ __launch_bounds__(256) void prep_kernel(
    const float* __restrict__ w0, const float* __restrict__ w1,
    const float* __restrict__ w2, const float* __restrict__ w3,
    const double* __restrict__ wsum, i8* __restrict__ q0, i8* __restrict__ q1,
    i8* __restrict__ q2, i8* __restrict__ q3, const float* __restrict__ X,
    const float* __restrict__ nw0, const float* __restrict__ nw1,
    const float* __restrict__ nw2, i8* __restrict__ Xq0, i8* __restrict__ Xq1,
    i8* __restrict__ Xq2, float* __restrict__ inv0, float* __restrict__ inv1,
    float* __restrict__ inv2) {
  if (blockIdx.x < 8192) {
    int sel = blockIdx.x >> 11;  // 0..3
    int blk = blockIdx.x & 2047;
    // sel: 0 -> w_f(widx1), 1 -> w_i(widx0), 2 -> w_g(widx2), 3 -> w_o(3)
    const float* w = sel == 0 ? w0 : sel == 1 ? w1 : sel == 2 ? w2 : w3;
    i8* wq = sel == 0 ? q0 : sel == 1 ? q1 : sel == 2 ? q2 : q3;
    int widx = sel == 0 ? 1 : sel == 1 ? 0 : sel;
    double mean = wsum[widx] * (1.0 / (double)WELEM);
    float s = (float)(1.0 / fmax(mean, 1e-5));
    size_t base = (size_t)blk * 2048 + (size_t)threadIdx.x * 8;
    float4 va = *(const float4*)&w[base];
    float4 vb = *(const float4*)&w[base + 4];
    float vv[8] = {va.x, va.y, va.z, va.w, vb.x, vb.y, vb.z, vb.w};
    int qi[8];
#pragma unroll
    for (int j = 0; j < 8; ++j) {
      float q1v = rintf(vv[j] * s);
      q1v = fminf(fmaxf(q1v, -1.0f), 1.0f);
      qi[j] = (int)q1v;
    }
    *(int2*)&wq[base] = make_int2(pack8(qi), pack8(qi + 4));
    return;
  }
  int tok = blockIdx.x - 8192;
  int tid = threadIdx.x;
  const float* xrow = X + (size_t)tok * HID;
  int c0 = tid * 8;
  float x[8];
  *(float4*)&x[0] = *(const float4*)&xrow[c0];
  *(float4*)&x[4] = *(const float4*)&xrow[c0 + 4];
  float ss = 0.0f;
#pragma unroll
  for (int j = 0; j < 8; ++j) ss += x[j] * x[j];
  __shared__ float sh[4];
  float v = wred_sum(ss);
  if ((tid & 63) == 0) sh[tid >> 6] = v;
  __syncthreads();
  float tot = (sh[0] + sh[1]) + (sh[2] + sh[3]);
  float rstd = (float)(1.0 / sqrt((double)(tot * (1.0f / HID)) + 1e-8));
#pragma unroll
  for (int pass = 0; pass < 3; ++pass) {
    const float* nw = pass == 0 ? nw0 : pass == 1 ? nw1 : nw2;
    i8* Xq = pass == 0 ? Xq0 : pass == 1 ? Xq1 : Xq2;
    float* inv_s = pass == 0 ? inv0 : pass == 1 ? inv1 : inv2;
    float y[8];
    float amax = 0.0f;
#pragma unroll
    for (int j = 0; j < 8; ++j) {
      y[j] = x[j] * rstd * nw[c0 + j];
      amax = fmaxf(amax, fabsf(y[j]));
    }
    __syncthreads();
    float vv = wred_max(amax);
    if ((tid & 63) == 0) sh[tid >> 6] = vv;
    __syncthreads();
    float am = fmaxf(fmaxf(fmaxf(sh[0], sh[1]), fmaxf(sh[2], sh[3])), 1e-5f);
    float s = 127.0f / am;
    int qi[8];
#pragma unroll
    for (int j = 0; j < 8; ++j) {
      float qq = rintf(y[j] * s);
      qq = fminf(fmaxf(qq, -128.0f), 127.0f);
      qi[j] = (int)qq;
    }
    *(int2*)&Xq[(size_t)tok * HID + c0] = make_int2(pack8(qi), pack8(qi + 4));
    if (tid == 0) inv_s[tok] = am * (1.0f / 127.0f);
  }
}

// ---------------- K4: i8 MFMA GEMM, 8 waves, BK=128, seg-merged -----------
// (R10-proven structure: best measured = 78us for 3 merged GEMMs.)
// out[m,n] = sum_k A[m,k]*W[n,k]; i32 accumulate (exact).
// NSEG=3: three independent GEMMs in one launch (seg = swz>>9); epilogue
//   per seg: 0 -> sigmoid (bf16), 1 -> silu (bf16), 2 -> raw (bf16).
// NSEG=1: single GEMM, raw f32 output.
// Block 128x128, wave (wm=wave>>2, wn=wave&3) owns 64x32.
// LDS swizzle: physical 16B slot = logical ^ (row&7); inverse on global
// source (linear gl_lds dest), forward on ds_read. 2 lanes/bank max.
template <int NSEG, bool F32OUT>
__global__ __launch_bounds__(512) void gemm8_kernel(
    const i8* __restrict__ A0, const i8* __restrict__ A1,
    const i8* __restrict__ A2, const i8* __restrict__ W0,
    const i8* __restrict__ W1, const i8* __restrict__ W2,
    const float* __restrict__ inv0, const float* __restrict__ inv1,
    const float* __restrict__ inv2, const double* __restrict__ wsum,
    int widx0, int widx1, int widx2, void* __restrict__ O0,
    void* __restrict__ O1, void* __restrict__ O2) {
  const int tid = threadIdx.x;
  // XCD-aware bijective swizzle (gridDim.x % 8 == 0)
  const int cpx = gridDim.x >> 3;
  const int lid = blockIdx.x;
  const int swz = (lid & 7) * cpx + (lid >> 3);
  const int seg = NSEG == 1 ? 0 : (swz >> 9);
  const int idx = swz & 511;
  const int n0 = (idx & 15) * 128;  // 16 n-tiles (HID/128)
  const int m0 = (idx >> 4) * 128;  // 32 m-tiles (TOKENS/128)

  const i8* Aq = seg == 0 ? A0 : seg == 1 ? A1 : A2;
  const i8* Wq = seg == 0 ? W0 : seg == 1 ? W1 : W2;
  const float* inv_s = seg == 0 ? inv0 : seg == 1 ? inv1 : inv2;
  void* Out = seg == 0 ? O0 : seg == 1 ? O1 : O2;
  const int widx = seg == 0 ? widx0 : seg == 1 ? widx1 : widx2;

  __shared__ __align__(16) i8 As[2][16384];
  __shared__ __align__(16) i8 Bs[2][16384];
  float wscale = (float)fmax(wsum[widx] * (1.0 / (double)WELEM), 1e-5);

  const int wave = tid >> 6, lane = tid & 63;
  const int wm = wave >> 2;                 // M half
  const int wn = wave & 3;                  // N quarter
  const int lrow = lane & 15;
  const int ksel = lane >> 4;               // 16B quarter within 64B half
  const int rsw = lrow & 7;                 // read-side swizzle key
  const int srow8 = lane >> 3;              // staging row within 8-row chunk
  const int scol = ((lane & 7) ^ srow8) << 4;  // inverse-swizzled byte col

  const i8* Ab = Aq + (size_t)m0 * HID;
  const i8* Wb = Wq + (size_t)n0 * HID;

  i32x4 acc[4][2];
#pragma unroll
  for (int i = 0; i < 4; ++i)
#pragma unroll
    for (int j = 0; j < 2; ++j)
#pragma unroll
      for (int r = 0; r < 4; ++r) acc[i][j][r] = 0;

  // staging: 16 chunks of 8 rows x 128B per matrix; 2 A + 2 B per wave
#define STAGE(buf, k0)                                                      \
  {                                                                         \
    _Pragma("unroll") for (int c = 0; c < 2; ++c) {                         \
      int chunk = wave * 2 + c;                                             \
      int row = chunk * 8 + srow8;                                          \
      gl_lds16(&Ab[(size_t)row * HID + (k0) + scol], &As[buf][chunk * 1024]); \
      gl_lds16(&Wb[(size_t)row * HID + (k0) + scol], &Bs[buf][chunk * 1024]); \
    }                                                                       \
  }

  const int NT = HID / 128;  // 16 K-steps
  STAGE(0, 0)
  __syncthreads();
  int cur = 0;
  for (int kt = 0; kt < NT; ++kt) {
    if (kt + 1 < NT) STAGE(cur ^ 1, (kt + 1) * 128)
    i32x4 af[4][2], bfr[2][2];
#pragma unroll
    for (int i = 0; i < 4; ++i) {
      int ra = wm * 64 + i * 16 + lrow;
#pragma unroll
      for (int kk = 0; kk < 2; ++kk) {
        int phys = ((kk << 2) | ksel) ^ rsw;
        af[i][kk] = *(const i32x4*)&As[cur][ra * 128 + phys * 16];
      }
    }
#pragma unroll
    for (int j = 0; j < 2; ++j) {
      int rb = wn * 32 + j * 16 + lrow;
#pragma unroll
      for (int kk = 0; kk < 2; ++kk) {
        int phys = ((kk << 2) | ksel) ^ rsw;
        bfr[j][kk] = *(const i32x4*)&Bs[cur][rb * 128 + phys * 16];
      }
    }
    __builtin_amdgcn_s_setprio(1);
#pragma unroll
    for (int kk = 0; kk < 2; ++kk)
#pragma unroll
      for (int i = 0; i < 4; ++i)
#pragma unroll
        for (int j = 0; j < 2; ++j)
          acc[i][j] = __builtin_amdgcn_mfma_i32_16x16x64_i8(
              af[i][kk], bfr[j][kk], acc[i][j], 0, 0, 0);
    __builtin_amdgcn_s_setprio(0);
    __syncthreads();  // drains prefetch vmcnt + protects LDS reuse
    cur ^= 1;
  }
#undef STAGE

#pragma unroll
  for (int i = 0; i < 4; ++i) {
    int rbase = m0 + wm * 64 + i * 16 + (lane >> 4) * 4;
#pragma unroll
    for (int j = 0; j < 2; ++j) {
      int col = n0 + wn * 32 + j * 16 + lrow;
#pragma unroll
      for (int r = 0; r < 4; ++r) {
        int row = rbase + r;
        float v = (float)acc[i][j][r] * inv_s[row] * wscale;
        float rr;
        if (NSEG == 3)
          rr = seg == 0 ? sigm(v) : seg == 1 ? v * sigm(v) : v;
        else
          rr = v;
        size_t oidx = (size_t)row * HID + col;
        if (F32OUT)
          ((float*)Out)[oidx] = rr;
        else
          ((u16*)Out)[oidx] = f2bf_rn(rr);
      }
    }
  }
}

// ---------------- K5: chunked parallel scan h = f*h + silu_i*(1-f) --------
// F, IO are bf16 (u16); P/H are f32.
__global__ __launch_bounds__(256) void scan1_kernel(
    const u16* __restrict__ F, u16* __restrict__ IO, float* __restrict__ P,
    float* __restrict__ H) {
  int c = blockIdx.x * 256 + threadIdx.x;
  int q = blockIdx.y;
  size_t base =
      (size_t)(c >> 11) * TT * HID + (c & 2047) + (size_t)q * CL * HID;
  float h = 0.0f, p = 1.0f;
#pragma unroll 4
  for (int t = 0; t < CL; ++t) {
    size_t idx = base + (size_t)t * HID;
    float f = bf2f(F[idx]);
    float iv = bf2f(IO[idx]);
    h = fmaf(f, h, iv - iv * f);  // f*h + silu_i*(1-f)
    p *= f;
    IO[idx] = f2bf_rn(h);
  }
  P[q * NCH + c] = p;
  H[q * NCH + c] = h;
}

// scan2 folded in: each block computes its chunk-prefix carry locally
// (identical fma order to the former scan2), then applies the fixup.
__global__ __launch_bounds__(256) void scan23_kernel(
    const u16* __restrict__ F, const float* __restrict__ P,
    const float* __restrict__ H, u16* __restrict__ IO) {
  int c = blockIdx.x * 256 + threadIdx.x;
  int q = blockIdx.y + 1;  // chunk 0 needs no fixup
  float carry = 0.0f;
  for (int qq = 0; qq < q; ++qq)
    carry = fmaf(P[qq * NCH + c], carry, H[qq * NCH + c]);
  if (carry == 0.0f) return;
  size_t base =
      (size_t)(c >> 11) * TT * HID + (c & 2047) + (size_t)q * CL * HID;
  float p = 1.0f;
#pragma unroll 4
  for (int t = 0; t < CL; ++t) {
    size_t idx = base + (size_t)t * HID;
    p *= bf2f(F[idx]);
    IO[idx] = f2bf_rn(fmaf(p, carry, bf2f(IO[idx])));
  }
}

// ---------------- K6: fused  o=rms(g)*o*sigm(o)  ->  rms(o,n_o)+quant -----
// G, O are bf16 (u16).
__global__ __launch_bounds__(256) void combine_quant_kernel(
    const u16* __restrict__ G, const float* __restrict__ gnw,
    const u16* __restrict__ O, const float* __restrict__ nw,
    i8* __restrict__ Xq, float* __restrict__ inv_s) {
  int tok = blockIdx.x;
  int tid = threadIdx.x;
  int c0 = tid * 8;
  const u16* grow = G + (size_t)tok * HID;
  const u16* orow = O + (size_t)tok * HID;
  ushort4 ga = *(const ushort4*)&grow[c0];
  ushort4 gb = *(const ushort4*)&grow[c0 + 4];
  ushort4 oa = *(const ushort4*)&orow[c0];
  ushort4 ob = *(const ushort4*)&orow[c0 + 4];
  float g[8] = {bf2f(ga.x), bf2f(ga.y), bf2f(ga.z), bf2f(ga.w),
                bf2f(gb.x), bf2f(gb.y), bf2f(gb.z), bf2f(gb.w)};
  float o[8] = {bf2f(oa.x), bf2f(oa.y), bf2f(oa.z), bf2f(oa.w),
                bf2f(ob.x), bf2f(ob.y), bf2f(ob.z), bf2f(ob.w)};
  __shared__ float sh[4];
  float ss = 0.0f;
#pragma unroll
  for (int j = 0; j < 8; ++j) ss += g[j] * g[j];
  float v = wred_sum(ss);
  if ((tid & 63) == 0) sh[tid >> 6] = v;
  __syncthreads();
  float tot = (sh[0] + sh[1]) + (sh[2] + sh[3]);
  float rstd_g = (float)(1.0 / sqrt((double)(tot * (1.0f / HID)) + 1e-5));
  float on[8];
  float ss2 = 0.0f;
#pragma unroll
  for (int j = 0; j < 8; ++j) {
    on[j] = g[j] * rstd_g * gnw[c0 + j] * o[j] * sigm(o[j]);
    ss2 += on[j] * on[j];
  }
  __syncthreads();
  v = wred_sum(ss2);
  if ((tid & 63) == 0) sh[tid >> 6] = v;
  __syncthreads();
  float tot2 = (sh[0] + sh[1]) + (sh[2] + sh[3]);
  float rstd_o = (float)(1.0 / sqrt((double)(tot2 * (1.0f / HID)) + 1e-8));
  float y[8];
  float amax = 0.0f;
#pragma unroll
  for (int j = 0; j < 8; ++j) {
    y[j] = on[j] * rstd_o * nw[c0 + j];
    amax = fmaxf(amax, fabsf(y[j]));
  }
  __syncthreads();
  v = wred_max(amax);
  if ((tid & 63) == 0) sh[tid >> 6] = v;
  __syncthreads();
  float am = fmaxf(fmaxf(fmaxf(sh[0], sh[1]), fmaxf(sh[2], sh[3])), 1e-5f);
  float s = 127.0f / am;
  int qi[8];
#pragma unroll
  for (int j = 0; j < 8; ++j) {
    float qq = rintf(y[j] * s);
    qq = fminf(fmaxf(qq, -128.0f), 127.0f);
    qi[j] = (int)qq;
  }
  *(int2*)&Xq[(size_t)tok * HID + c0] = make_int2(pack8(qi), pack8(qi + 4));
  if (tid == 0) inv_s[tok] = am * (1.0f / 127.0f);
}

extern "C" void kernel_launch(void* const* d_in, const int* in_sizes, int n_in,
                              void* d_out, int out_size, void* d_ws,
                              size_t ws_size, hipStream_t stream) {
  const float* hs = (const float*)d_in[0];
  const float* w_i = (const float*)d_in[1];
  const float* w_f = (const float*)d_in[2];
  const float* w_g = (const float*)d_in[3];
  const float* w_o = (const float*)d_in[4];
  const float* n_i = (const float*)d_in[5];
  const float* n_f = (const float*)d_in[6];
  const float* n_g = (const float*)d_in[7];
  const float* n_o = (const float*)d_in[8];
  const float* gn_w = (const float*)d_in[9];
  float* Out = (float*)d_out;

  char* ws = (char*)d_ws;
  // Layout (~93.4MB of ~256MB ws)
  i8* WQ0 = (i8*)ws;                       // w_f ternary
  i8* WQ1 = (i8*)(ws + 4194304);           // w_i
  i8* WQ2 = (i8*)(ws + 8388608);           // w_g
  i8* WQ3 = (i8*)(ws + 12582912);          // w_o
  i8* XQ0 = (i8*)(ws + 16777216);          // f-quant, later o-quant
  i8* XQ1 = (i8*)(ws + 25165824);          // i-quant
  i8* XQ2 = (i8*)(ws + 33554432);          // g-quant
  u16* F = (u16*)(ws + 41943040);          // f gate (bf16)
  u16* OB = (u16*)(ws + 58720256);         // i -> scan h -> o (bf16)
  u16* G = (u16*)(ws + 75497472);          // g (bf16)
  float* invs0 = (float*)(ws + 92274688);
  float* invs1 = (float*)(ws + 92291072);
  float* invs2 = (float*)(ws + 92307456);
  double* wsum = (double*)(ws + 92323840);
  float* scanP = (float*)(ws + 92324864);
  float* scanH = (float*)(ws + 92849152);

  hipMemsetAsync(wsum, 0, 4 * sizeof(double), stream);
  // wsum order: 0=i, 1=f, 2=g, 3=o
  absmean_kernel<<<2048, 256, 0, stream>>>(w_i, w_f, w_g, w_o, wsum);

  // fused: quantize all 4 weights + 3 activation norms in one launch
  prep_kernel<<<12288, 256, 0, stream>>>(w_f, w_i, w_g, w_o, wsum, WQ0, WQ1,
                                         WQ2, WQ3, hs, n_f, n_i, n_g, XQ0,
                                         XQ1, XQ2, invs0, invs1, invs2);

  // merged: F = sigm(hs*Wf), OB = silu(hs*Wi), G = hs*Wg  (1536 blocks)
  gemm8_kernel<3, false><<<1536, 512, 0, stream>>>(
      XQ0, XQ1, XQ2, WQ0, WQ1, WQ2, invs0, invs1, invs2, wsum, 1, 0, 2, F, OB,
      G);

  // scan: h_t = f_t*h + silu_i_t*(1-f_t), in-place in OB (bf16)
  scan1_kernel<<<dim3(NCH / 256, NC), 256, 0, stream>>>(F, OB, scanP, scanH);
  scan23_kernel<<<dim3(NCH / 256, NC - 1), 256, 0, stream>>>(F, scanP, scanH,
                                                             OB);

  // fused: o = rms(g)*o*sigm(o); then rms(o, n_o) + act-quant -> XQ0
  combine_quant_kernel<<<TOKENS, 256, 0, stream>>>(G, gn_w, OB, n_o, XQ0,
                                                   invs0);

  // out = bitlinear(o, w_o, n_o)  (f32 output)
  gemm8_kernel<1, true><<<512, 512, 0, stream>>>(
      XQ0, XQ0, XQ0, WQ3, WQ3, WQ3, invs0, invs0, invs0, wsum, 3, 3, 3, Out,
      Out, Out);
}